// Round 2
// baseline (773.470 us; speedup 1.0000x reference)
//
#include <hip/hip_runtime.h>

#define ALPHA 0.1f
#define HDEPTH 8
#define STEPS 6            // H - 2
#define NCLASS 10000
#define NNODES 15000
#define BATCH 1024
#define NPAIRS (BATCH * STEPS)   // 6144
#define ROW_WORDS 320            // u32 words per packed row (1280 B, padded)
#define ROW_QWORDS 160           // u64 words per packed row
#define CHUNK 128                // pairs per y-block
#define NCHUNK (NPAIRS / CHUNK)  // 48

// ---------------------------------------------------------------------------
// ws layout:
//   [0,        48 KiB)  : pairs  int2[6144]
//   [64 KiB,  124 KiB)  : flags  int[15000]
//   [128 KiB, +19.2 MiB): packed L bits, u32[15000*320]
// ---------------------------------------------------------------------------

// Kernel 1: build (n1,n2) pairs (s-major: s = p>>10) and flag touched nodes.
__global__ void build_pairs_kernel(const int* __restrict__ target,
                                   const int* __restrict__ path,
                                   int2* __restrict__ pairs,
                                   int* __restrict__ flags) {
    int p = blockIdx.x * blockDim.x + threadIdx.x;
    if (p >= NPAIRS) return;
    int s = p >> 10;          // BATCH == 1024
    int b = p & (BATCH - 1);
    int t = target[b];
    int n1 = path[t * HDEPTH + s];
    int n2 = path[t * HDEPTH + s + 1];
    pairs[p] = make_int2(n1, n2);
    flags[n1] = 1;            // benign race: same value
    flags[n2] = 1;
}

// Kernel 2: bit-pack touched rows of L. One block per row; wave ballot packs
// 64 classes per wave per iteration. Untouched rows early-exit (uniform).
__global__ void __launch_bounds__(256)
pack_rows_kernel(const int* __restrict__ L,
                 const int* __restrict__ flags,
                 unsigned long long* __restrict__ bits) {
    const int row = blockIdx.x;
    if (!flags[row]) return;                      // block-uniform
    const int wave = threadIdx.x >> 6;            // 0..3
    const int lane = threadIdx.x & 63;
    const int* Lrow = L + (size_t)row * NCLASS;
    unsigned long long* brow = bits + (size_t)row * ROW_QWORDS;
    // 40 iterations of 256 cover 10240 >= NCLASS; writes all 160 qwords.
    for (int base = 0; base < 40 * 256; base += 256) {
        int c = base + threadIdx.x;
        int pred = (c < NCLASS) ? (Lrow[c] > 1) : 0;
        unsigned long long m = __ballot(pred);
        if (lane == 0) brow[(base >> 6) + wave] = m;
    }
}

// Kernel 3: main accumulation over packed bits.
// grid.x: classes (1 thread = 1 class), grid.y: pair chunks of 128.
// ratio lut: (b1,b2) -> {(0,0):1, (1,1):1, (1,0):2, (0,1):0.5}
__global__ void __launch_bounds__(256)
hce_main_kernel(const unsigned int* __restrict__ bits,
                const int2* __restrict__ pairs,
                float* __restrict__ out) {
    __shared__ int2 s_pairs[CHUNK];
    __shared__ float s_w[CHUNK];

    const int c = blockIdx.x * 256 + threadIdx.x;
    const int word = c >> 5;                      // < 320, safe even for c>=NCLASS
    const int bit = c & 31;

    const int p0 = blockIdx.y * CHUNK;
    if (threadIdx.x < CHUNK) {
        int p = p0 + threadIdx.x;
        s_pairs[threadIdx.x] = pairs[p];
        s_w[threadIdx.x] = __expf(-ALPHA * (float)(HDEPTH - 1 - (p >> 10)));
    }
    __syncthreads();

    float acc = 0.f;
#pragma unroll 4
    for (int i = 0; i < CHUNK; ++i) {
        int2 pr = s_pairs[i];                     // broadcast, conflict-free
        float w = s_w[i];
        unsigned int m1 = bits[pr.x * ROW_WORDS + word];
        unsigned int m2 = bits[pr.y * ROW_WORDS + word];
        unsigned int b1 = (m1 >> bit) & 1u;
        unsigned int b2 = (m2 >> bit) & 1u;
        float r = (b1 == b2) ? 1.0f : (b1 ? 2.0f : 0.5f);
        acc += w * r;
    }
    if (c < NCLASS)
        atomicAdd(out + c, -acc * (1.0f / (float)BATCH));
}

extern "C" void kernel_launch(void* const* d_in, const int* in_sizes, int n_in,
                              void* d_out, int out_size, void* d_ws, size_t ws_size,
                              hipStream_t stream) {
    // inputs: [0] logits (cancels exactly), [1] target_classes, [2] L, [3] path
    const int* target = (const int*)d_in[1];
    const int* L      = (const int*)d_in[2];
    const int* path   = (const int*)d_in[3];
    float* out        = (float*)d_out;

    char* ws = (char*)d_ws;
    int2* pairs                = (int2*)(ws);
    int* flags                 = (int*)(ws + 64 * 1024);
    unsigned long long* bits64 = (unsigned long long*)(ws + 128 * 1024);
    unsigned int* bits32       = (unsigned int*)(ws + 128 * 1024);

    hipMemsetAsync(out, 0, NCLASS * sizeof(float), stream);
    hipMemsetAsync(flags, 0, NNODES * sizeof(int), stream);

    build_pairs_kernel<<<(NPAIRS + 255) / 256, 256, 0, stream>>>(target, path, pairs, flags);
    pack_rows_kernel<<<NNODES, 256, 0, stream>>>(L, flags, bits64);

    dim3 grid((NCLASS + 255) / 256, NCHUNK);   // (40, 48)
    hce_main_kernel<<<grid, 256, 0, stream>>>(bits32, pairs, out);
}

// Round 3
// 739.996 us; speedup vs baseline: 1.0452x; 1.0452x over previous
//
#include <hip/hip_runtime.h>

#define ALPHA 0.1f
#define HDEPTH 8
#define STEPS 6            // H - 2
#define NCLASS 10000
#define NNODES 15000
#define BATCH 1024
#define NPAIRS (BATCH * STEPS)   // 6144
#define ROW_WORDS 320            // u32 words per packed row (1280 B, padded)
#define NV4 2500                 // int4 elements per L row (NCLASS/4)
#define CHUNK 128                // pairs per y-block
#define NCHUNK (NPAIRS / CHUNK)  // 48

// ---------------------------------------------------------------------------
// ws layout:
//   [0,        48 KiB)  : pairs  int2[6144]
//   [64 KiB,  124 KiB)  : flags  int[15000]
//   [128 KiB, +19.2 MiB): packed L bits, u32[15000*320]
// ---------------------------------------------------------------------------

// Kernel 1: build (n1,n2) pairs (s-major: s = p>>10) and flag touched nodes.
__global__ void build_pairs_kernel(const int* __restrict__ target,
                                   const int* __restrict__ path,
                                   int2* __restrict__ pairs,
                                   int* __restrict__ flags) {
    int p = blockIdx.x * blockDim.x + threadIdx.x;
    if (p >= NPAIRS) return;
    int s = p >> 10;          // BATCH == 1024
    int b = p & (BATCH - 1);
    int t = target[b];
    int n1 = path[t * HDEPTH + s];
    int n2 = path[t * HDEPTH + s + 1];
    pairs[p] = make_int2(n1, n2);
    flags[n1] = 1;            // benign race: same value
    flags[n2] = 1;
}

// spread bit i of an 8-bit value to bit 4i of a 32-bit word
__device__ __forceinline__ unsigned int spread4(unsigned int x) {
    x &= 0xFFu;
    x = (x | (x << 12)) & 0x000F000Fu;
    x = (x | (x << 6))  & 0x03030303u;
    x = (x | (x << 3))  & 0x11111111u;
    return x;
}

// Kernel 2: bit-pack touched rows of L with int4 (16B/lane) streaming loads.
// One block per row. Per wave-iteration: 64 lanes x int4 = 256 classes
// = 8 output u32 words, assembled via 4 ballots + in-register interleave.
// Untouched rows early-exit (block-uniform). 10 iters * 1024 covers NCLASS.
__global__ void __launch_bounds__(256)
pack_rows_kernel(const int4* __restrict__ L4,
                 const int* __restrict__ flags,
                 unsigned int* __restrict__ bits) {
    const int row = blockIdx.x;
    if (!flags[row]) return;                      // block-uniform
    const int wave = threadIdx.x >> 6;            // 0..3
    const int lane = threadIdx.x & 63;
    const int4* Lrow = L4 + (size_t)row * NV4;
    unsigned int* brow = bits + (size_t)row * ROW_WORDS;

    for (int it = 0; it < 10; ++it) {
        int v = it * 256 + wave * 64 + lane;      // int4 index within row
        int4 q = (v < NV4) ? Lrow[v] : make_int4(1, 1, 1, 1);
        // ballot_k bit L  <->  class base + 4L + k  (base = 1024*it + 256*wave)
        unsigned long long b0 = __ballot(q.x > 1);
        unsigned long long b1 = __ballot(q.y > 1);
        unsigned long long b2 = __ballot(q.z > 1);
        unsigned long long b3 = __ballot(q.w > 1);
        if (lane < 8) {
            // word j (j=lane) covers classes base + 32j .. +32:
            // bit b -> L = 8j + (b>>2), k = b&3
            unsigned int w =  spread4((unsigned int)(b0 >> (8 * lane)))
                           | (spread4((unsigned int)(b1 >> (8 * lane))) << 1)
                           | (spread4((unsigned int)(b2 >> (8 * lane))) << 2)
                           | (spread4((unsigned int)(b3 >> (8 * lane))) << 3);
            brow[it * 32 + wave * 8 + lane] = w;  // max index 319 < ROW_WORDS
        }
    }
}

// Kernel 3: main accumulation over packed bits.
// grid.x: classes (1 thread = 1 class), grid.y: pair chunks of 128.
__global__ void __launch_bounds__(256)
hce_main_kernel(const unsigned int* __restrict__ bits,
                const int2* __restrict__ pairs,
                float* __restrict__ out) {
    __shared__ int2 s_pairs[CHUNK];
    __shared__ float s_w[CHUNK];

    const int c = blockIdx.x * 256 + threadIdx.x;
    const int word = c >> 5;                      // <= 319, safe even for c>=NCLASS
    const int bit = c & 31;

    const int p0 = blockIdx.y * CHUNK;
    if (threadIdx.x < CHUNK) {
        int p = p0 + threadIdx.x;
        s_pairs[threadIdx.x] = pairs[p];
        s_w[threadIdx.x] = __expf(-ALPHA * (float)(HDEPTH - 1 - (p >> 10)));
    }
    __syncthreads();

    float acc = 0.f;
#pragma unroll 4
    for (int i = 0; i < CHUNK; ++i) {
        int2 pr = s_pairs[i];                     // broadcast, conflict-free
        float w = s_w[i];
        unsigned int m1 = bits[pr.x * ROW_WORDS + word];
        unsigned int m2 = bits[pr.y * ROW_WORDS + word];
        unsigned int b1 = (m1 >> bit) & 1u;
        unsigned int b2 = (m2 >> bit) & 1u;
        float r = (b1 == b2) ? 1.0f : (b1 ? 2.0f : 0.5f);
        acc += w * r;
    }
    if (c < NCLASS)
        atomicAdd(out + c, -acc * (1.0f / (float)BATCH));
}

extern "C" void kernel_launch(void* const* d_in, const int* in_sizes, int n_in,
                              void* d_out, int out_size, void* d_ws, size_t ws_size,
                              hipStream_t stream) {
    // inputs: [0] logits (cancels exactly — ratios are {0.5,1,2} bit-exactly),
    //         [1] target_classes, [2] L, [3] path_to_root
    const int* target = (const int*)d_in[1];
    const int4* L4    = (const int4*)d_in[2];
    const int* path   = (const int*)d_in[3];
    float* out        = (float*)d_out;

    char* ws = (char*)d_ws;
    int2* pairs          = (int2*)(ws);
    int* flags           = (int*)(ws + 64 * 1024);
    unsigned int* bits32 = (unsigned int*)(ws + 128 * 1024);

    hipMemsetAsync(out, 0, NCLASS * sizeof(float), stream);
    hipMemsetAsync(flags, 0, NNODES * sizeof(int), stream);

    build_pairs_kernel<<<(NPAIRS + 255) / 256, 256, 0, stream>>>(target, path, pairs, flags);
    pack_rows_kernel<<<NNODES, 256, 0, stream>>>(L4, flags, bits32);

    dim3 grid((NCLASS + 255) / 256, NCHUNK);   // (40, 48)
    hce_main_kernel<<<grid, 256, 0, stream>>>(bits32, pairs, out);
}